// Round 16
// baseline (219.381 us; speedup 1.0000x reference)
//
#include <hip/hip_runtime.h>

#define BB 8
#define TT 1024
#define DD 512
#define DD2 1024
#define HH 8
#define HDIM 64
#define TP (TT + 2)

typedef short short8 __attribute__((ext_vector_type(8)));
typedef float floatx4 __attribute__((ext_vector_type(4)));

typedef const __attribute__((address_space(1))) unsigned int* gas_ptr;
typedef __attribute__((address_space(3))) unsigned int* las_ptr;

__device__ __forceinline__ unsigned short f2bf(float f) {
    union { float f; unsigned u; } v; v.f = f;
    unsigned r = v.u + 0x7fffu + ((v.u >> 16) & 1u);
    return (unsigned short)(r >> 16);
}

// async global->LDS, 16B per lane, LDS dst = wave-uniform base + lane*16
__device__ __forceinline__ void gl2lds16(const void* g, void* l) {
    __builtin_amdgcn_global_load_lds((gas_ptr)g, (las_ptr)l, 16, 0, 0);
}

// ---------------- fused prep kernel (R15-proven) ----------------
#define NX4BLK 2052   // 8*1026*512/8/256
#define NW1BLK 3072   // 9*512*512/3/256
#define NW2BLK 2048   // 3*512*1024/3/256
#define NZBLK 1024
__global__ void k_prep(const float* __restrict__ x, const float* __restrict__ w0,
                       const float* __restrict__ w1, const float* __restrict__ w2,
                       const float* __restrict__ wo,
                       unsigned short* __restrict__ xp, unsigned short* __restrict__ wqkv,
                       unsigned short* __restrict__ w2k, unsigned short* __restrict__ vp,
                       float* __restrict__ gbuf) {
    int blk = blockIdx.x;
    if (blk < NX4BLK) {
        int idx = blk * 256 + threadIdx.x;
        int c8 = idx & 63;          // DD/8 = 64 chunks per row
        int rt = idx >> 6;
        int row = rt % TP;
        int b = rt / TP;
        ushort4 o0 = {0, 0, 0, 0}, o1 = {0, 0, 0, 0};
        if (row >= 1 && row <= TT) {
            const float* src = &x[((size_t)(b * TT + row - 1)) * DD + c8 * 8];
            float4 va = *(const float4*)src;
            float4 vb = *(const float4*)(src + 4);
            o0.x = f2bf(va.x); o0.y = f2bf(va.y); o0.z = f2bf(va.z); o0.w = f2bf(va.w);
            o1.x = f2bf(vb.x); o1.y = f2bf(vb.y); o1.z = f2bf(vb.z); o1.w = f2bf(vb.w);
        }
        *(ushort4*)&xp[(size_t)idx * 8] = o0;
        *(ushort4*)&xp[(size_t)idx * 8 + 4] = o1;
        return;
    }
    blk -= NX4BLK;
    if (blk < NW1BLK) {
        // W(qkv) B-frag-major: [proj][k][ci0(16)][co0(32)][lane(64)][e(8)]
        int idx = blk * 256 + threadIdx.x;      // [0, 786432)
        int e = idx & 7;
        int lane = (idx >> 3) & 63;
        int co0 = (idx >> 9) & 31;
        int ci0 = (idx >> 14) & 15;
        int p = idx >> 18;
        int base18 = idx & 0x3FFFF;
        int co = co0 * 16 + (lane & 15);
        int ci = ci0 * 32 + (lane >> 4) * 8 + e;
        const float* w = (p == 0) ? w0 : ((p == 1) ? w1 : w2);
        size_t src = (size_t)(co * DD + ci) * 3;
        float t0 = w[src], t1 = w[src + 1], t2 = w[src + 2];
        wqkv[((size_t)(p * 3 + 0) << 18) + base18] = f2bf(t0);
        wqkv[((size_t)(p * 3 + 1) << 18) + base18] = f2bf(t1);
        wqkv[((size_t)(p * 3 + 2) << 18) + base18] = f2bf(t2);
        return;
    }
    blk -= NW1BLK;
    if (blk < NW2BLK) {
        // W2 B-frag-major: [k][ci0(32)][co0(32)][lane(64)][e(8)]; 3 taps per thread.
        int idx = blk * 256 + threadIdx.x;      // [0, 524288)
        int e = idx & 7;
        int lane = (idx >> 3) & 63;
        int co0 = (idx >> 9) & 31;
        int ci0 = (idx >> 14) & 31;
        int co = co0 * 16 + (lane & 15);
        int ci = ci0 * 32 + (lane >> 4) * 8 + e;
        size_t src = (size_t)(co * DD2 + ci) * 3;
        float t0 = wo[src], t1 = wo[src + 1], t2 = wo[src + 2];
        w2k[((size_t)0 << 19) + idx] = f2bf(t0);
        w2k[((size_t)1 << 19) + idx] = f2bf(t1);
        w2k[((size_t)2 << 19) + idx] = f2bf(t2);
        return;
    }
    blk -= NW2BLK;
    {
        int idx = blk * 256 + threadIdx.x;
        if (idx < BB * 2 * 2 * DD) {
            int c = idx % (2 * DD);
            int t1 = idx / (2 * DD);
            int row = (t1 & 1) ? (TT + 1) : 0;
            int b = t1 >> 1;
            vp[(b * TP + row) * (2 * DD) + c] = 0;
        }
        if (idx < 64 * HDIM * HDIM) gbuf[idx] = 0.f;
    }
}

// ---------------- QKV conv: R3-proven 64x128 tile, BK=64 2-phase dbuf ----------
// 1D grid 1536 = 6/CU, XCD-swizzled (T1, R13-verified: FETCH 47->26.7 MB).
__global__ __launch_bounds__(256) void k_qkv_conv(
    const unsigned short* __restrict__ xp, const unsigned short* __restrict__ wfrag,
    const float* __restrict__ b11, const float* __restrict__ b12, const float* __restrict__ b13,
    unsigned short* __restrict__ q, unsigned short* __restrict__ qt,
    unsigned short* __restrict__ kfrag, unsigned short* __restrict__ kt,
    unsigned short* __restrict__ v, unsigned short* __restrict__ vtfrag) {
    __shared__ short As[2][80 * 64];
    int wave = threadIdx.x >> 6, lane = threadIdx.x & 63;
    int l15 = lane & 15, quad = lane >> 4;
    int i = blockIdx.x;
    int w = (i & 7) * 192 + (i >> 3);   // XCD-contiguous work chunks
    int tb = (w & 15) * 64;
    int cb = ((w >> 4) & 3) * 128;
    int z = w >> 6;
    int proj = z % 3, b = z / 3;
    const short* A = (const short*)xp + b * TP * DD;
    const short* WF = (const short*)wfrag + (size_t)proj * 786432 + lane * 8;
    int srow8 = lane >> 3;
    int scl = ((lane & 7) ^ srow8) * 8;
    int co0b = (cb >> 4) + wave * 2;

    floatx4 acc[4][2];
#pragma unroll
    for (int mi = 0; mi < 4; ++mi)
#pragma unroll
        for (int ni = 0; ni < 2; ++ni) acc[mi][ni] = (floatx4){0.f, 0.f, 0.f, 0.f};

    auto stage = [&](int it) {
        short* dst = As[it & 1];
        int cib = it * 64;
        for (int g = wave; g < 10; g += 4) {
            int j = g >> 1, hf = g & 1;
            int row = hf * 8 + srow8;
            gl2lds16(A + (tb + j * 16 + row) * DD + cib + scl, &dst[j * 1024 + hf * 512]);
        }
    };

    stage(0);
    __syncthreads();

    for (int it = 0; it < 8; ++it) {
        if (it < 7) stage(it + 1);
        const short* Asb = As[it & 1];
#pragma unroll
        for (int k = 0; k < 3; ++k) {
            short8 bf[2][2];
#pragma unroll
            for (int kf = 0; kf < 2; ++kf)
#pragma unroll
                for (int ni = 0; ni < 2; ++ni)
                    bf[kf][ni] = *(const short8*)(WF +
                        ((size_t)((k * 16 + it * 2 + kf) * 32 + co0b + ni) << 9));
#pragma unroll
            for (int kf = 0; kf < 2; ++kf) {
                short8 af[4];
#pragma unroll
                for (int mi = 0; mi < 4; ++mi) {
                    int arow = mi * 16 + l15 + k;
                    int cl = kf * 4 + quad;
                    af[mi] = *(const short8*)&Asb[arow * 64 + ((cl ^ (arow & 7)) << 3)];
                }
#pragma unroll
                for (int mi = 0; mi < 4; ++mi)
#pragma unroll
                    for (int ni = 0; ni < 2; ++ni)
                        acc[mi][ni] = __builtin_amdgcn_mfma_f32_16x16x32_bf16(af[mi], bf[kf][ni], acc[mi][ni], 0, 0, 0);
            }
        }
        __syncthreads();
    }

    const float* bias = (proj == 0) ? b11 : ((proj == 1) ? b12 : b13);
#pragma unroll
    for (int ni = 0; ni < 2; ++ni) {
        int co = cb + wave * 32 + ni * 16 + l15;
        float bv = bias[co];
        int h = co >> 6, hd = co & 63;
        int bh = b * HH + h;
#pragma unroll
        for (int mi = 0; mi < 4; ++mi) {
            int tbase = tb + mi * 16 + quad * 4;
            unsigned short bb[4];
            ushort4 pk;
#pragma unroll
            for (int r = 0; r < 4; ++r) {
                float val = fmaxf(acc[mi][ni][r] + bv, 0.f);
                bb[r] = f2bf(val);
                ((unsigned short*)&pk)[r] = bb[r];
            }
            if (proj == 0) {
#pragma unroll
                for (int r = 0; r < 4; ++r)
                    q[((size_t)bh * TT + tbase + r) * HDIM + hd] = bb[r];
                *(ushort4*)&qt[((size_t)bh * HDIM + hd) * TT + tbase] = pk;
            } else if (proj == 1) {
                *(ushort4*)&kt[((size_t)bh * HDIM + hd) * TT + tbase] = pk;
                // K-frag layout: [bh][sblk][jr][kf][quad_a*16+l15a][8]
                int sblk = tbase >> 6;
                int jr = (quad & 1) + 2 * (mi >> 1);
                int l15a_base = 4 * (quad >> 1) + 8 * (mi & 1);  // + r
                int kf = hd >> 5, quad_a = (hd >> 3) & 3, elem = hd & 7;
                size_t base = ((((size_t)bh * 16 + sblk) * 4 + jr) * 2 + kf) * 512 +
                              quad_a * 128 + elem;
#pragma unroll
                for (int r = 0; r < 4; ++r)
                    kfrag[base + (l15a_base + r) * 8] = bb[r];
            } else {
#pragma unroll
                for (int r = 0; r < 4; ++r)
                    v[((size_t)bh * TT + tbase + r) * HDIM + hd] = bb[r];
                // Vt-frag layout: [bh][sblk][df][kf][quad_a*16+l15a][8]
                int sblk = tbase >> 6;
                int df = hd >> 4, l15a = hd & 15;
                int kf = mi >> 1;
                int quad_a = 2 * (mi & 1) + (quad >> 1);
                int elem = (quad & 1) * 4;
                size_t base = ((((size_t)bh * 16 + sblk) * 4 + df) * 2 + kf) * 512 +
                              (quad_a * 16 + l15a) * 8 + elem;
                *(ushort4*)&vtfrag[base] = pk;
            }
        }
    }
}

// ---------------- fused: time attention (x<16) + chan Gram full (x==16) ----------
// 1D grid 1088 = 17 blocks/bh, XCD-swizzled (136/XCD = exactly 8 bh). Gram now
// computed full-K by ONE block per bh (plain store) — removes ~1M device atomics.
__global__ __launch_bounds__(256) void k_attn_gram(
    const unsigned short* __restrict__ q, const unsigned short* __restrict__ kfrag,
    const unsigned short* __restrict__ vtfrag, const unsigned short* __restrict__ qt,
    const unsigned short* __restrict__ kt, float* __restrict__ gbuf,
    unsigned short* __restrict__ vp) {
    __shared__ short kvs[2][8192];  // [buf][ K frags 0..4095 | V frags 4096..8191 ]
    int wave = threadIdx.x >> 6, lane = threadIdx.x & 63;
    int l15 = lane & 15, quad = lane >> 4;
    int i = blockIdx.x;
    int w = (i & 7) * 136 + (i >> 3);   // XCD-contiguous chunks of 8 bh
    int bh = w / 17;
    int x = w % 17;

    if (x < 16) {
        // ---- time attention: all-register flash, LDS-staged K/V frags ----
        int b = bh >> 3, h = bh & 7;
        int qr = x * 64 + wave * 16;
        const short* Q = (const short*)q + (size_t)bh * TT * HDIM;
        const short* KF = (const short*)kfrag + (size_t)bh * 16 * 8 * 512 + lane * 8;
        const short* VF = (const short*)vtfrag + (size_t)bh * 16 * 8 * 512 + lane * 8;

        short8 bq[2];
#pragma unroll
        for (int kf = 0; kf < 2; ++kf)
            bq[kf] = *(const short8*)(Q + (qr + l15) * HDIM + kf * 32 + quad * 8);

        floatx4 o[4];  // O^T accum: d = df*16 + quad*4 + r, q = l15
#pragma unroll
        for (int df = 0; df < 4; ++df) o[df] = (floatx4){0.f, 0.f, 0.f, 0.f};
        float lacc = 0.f;

        auto stagekv = [&](int s) {
            short* dst = kvs[s & 1];
            for (int f = wave; f < 8; f += 4) {
                gl2lds16(KF + s * 4096 + f * 512, &dst[f * 512]);
                gl2lds16(VF + s * 4096 + f * 512, &dst[4096 + f * 512]);
            }
        };

        stagekv(0);
        __syncthreads();

        for (int sblk = 0; sblk < 16; ++sblk) {
            if (sblk < 15) stagekv(sblk + 1);
            const short* kb = (const short*)&kvs[sblk & 1][0] + lane * 8;
            const short* vb = kb + 4096;
            floatx4 c[4];
#pragma unroll
            for (int jr = 0; jr < 4; ++jr) c[jr] = (floatx4){0.f, 0.f, 0.f, 0.f};
#pragma unroll
            for (int jr = 0; jr < 4; ++jr) {
#pragma unroll
                for (int kf = 0; kf < 2; ++kf) {
                    short8 ak = *(const short8*)(kb + (jr * 2 + kf) * 512);
                    c[jr] = __builtin_amdgcn_mfma_f32_16x16x32_bf16(ak, bq[kf], c[jr], 0, 0, 0);
                }
            }
            short8 pb[2];
#pragma unroll
            for (int kf = 0; kf < 2; ++kf) {
                union { short8 s; unsigned u[4]; } pk;
#pragma unroll
                for (int half = 0; half < 2; ++half) {
                    floatx4 cc = c[2 * kf + half];
                    float p0 = __expf(cc[0] * 0.125f);
                    float p1 = __expf(cc[1] * 0.125f);
                    float p2 = __expf(cc[2] * 0.125f);
                    float p3 = __expf(cc[3] * 0.125f);
                    lacc += (p0 + p1) + (p2 + p3);
                    pk.u[half * 2] =
                        __builtin_amdgcn_perm(__float_as_uint(p1), __float_as_uint(p0), 0x07060302u);
                    pk.u[half * 2 + 1] =
                        __builtin_amdgcn_perm(__float_as_uint(p3), __float_as_uint(p2), 0x07060302u);
                }
                pb[kf] = pk.s;
            }
#pragma unroll
            for (int df = 0; df < 4; ++df) {
#pragma unroll
                for (int kf = 0; kf < 2; ++kf) {
                    short8 av = *(const short8*)(vb + (df * 2 + kf) * 512);
                    o[df] = __builtin_amdgcn_mfma_f32_16x16x32_bf16(av, pb[kf], o[df], 0, 0, 0);
                }
            }
            __syncthreads();
        }

        lacc += __shfl_xor(lacc, 16);
        lacc += __shfl_xor(lacc, 32);
        float linv = 1.f / lacc;

        unsigned short* vrow = vp + (size_t)(b * TP + 1 + qr + l15) * (2 * DD) + h * 64;
#pragma unroll
        for (int df = 0; df < 4; ++df) {
            ushort4 pk;
#pragma unroll
            for (int r = 0; r < 4; ++r) ((unsigned short*)&pk)[r] = f2bf(o[df][r] * linv);
            *(ushort4*)&vrow[df * 16 + quad * 4] = pk;
        }
    } else {
        // ---- chan Gram, full K range, one block per bh, plain store ----
        const short* Qt = (const short*)qt + (size_t)bh * HDIM * TT;
        const short* Kt = (const short*)kt + (size_t)bh * HDIM * TT;

        floatx4 g[4];
#pragma unroll
        for (int nt = 0; nt < 4; ++nt) g[nt] = (floatx4){0.f, 0.f, 0.f, 0.f};

        for (int t0 = 0; t0 < TT; t0 += 32) {
            short8 aq = *(const short8*)(Qt + (wave * 16 + l15) * TT + t0 + quad * 8);
#pragma unroll
            for (int nt = 0; nt < 4; ++nt) {
                short8 bk = *(const short8*)(Kt + (nt * 16 + l15) * TT + t0 + quad * 8);
                g[nt] = __builtin_amdgcn_mfma_f32_16x16x32_bf16(aq, bk, g[nt], 0, 0, 0);
            }
        }
        float* gb = gbuf + bh * HDIM * HDIM;
#pragma unroll
        for (int nt = 0; nt < 4; ++nt) {
#pragma unroll
            for (int r = 0; r < 4; ++r) {
                int row = wave * 16 + quad * 4 + r;
                gb[row * HDIM + nt * 16 + l15] = g[nt][r];
            }
        }
    }
}

// ---------------- channel attention: all-8-heads blocks, coalesced vp writes --------
// grid (32, B=8) = 256 blocks = 1/CU. Full-line vp writes from one block. (R7/R10-proven)
__global__ __launch_bounds__(256) void k_chan_av(
    const float* __restrict__ gbuf, const unsigned short* __restrict__ v,
    unsigned short* __restrict__ vp) {
    __shared__ short lds_a[8 * 64 * 64];   // 64 KB
    __shared__ short stg[64 * 128];        // 16 KB
    int wave = threadIdx.x >> 6, lane = threadIdx.x & 63;
    int l15 = lane & 15, quad = lane >> 4;
    int tc = blockIdx.x, b = blockIdx.y;
    const float sc = 0.03125f;  // 1/sqrt(1024)

    // softmax for all 8 heads: 512 rows over 256 threads
    for (int p = threadIdx.x; p < 512; p += 256) {
        int h = p >> 6, row = p & 63;
        const float* gb = gbuf + (size_t)((b * 8 + h) * 64 + row) * 64;
        float mx = -3.0e38f;
        for (int j = 0; j < 16; ++j) {
            float4 vv = *(const float4*)&gb[j * 4];
            mx = fmaxf(mx, fmaxf(fmaxf(vv.x, vv.y), fmaxf(vv.z, vv.w)));
        }
        mx *= sc;
        float sum = 0.f;
        for (int j = 0; j < 64; ++j) sum += __expf(gb[j] * sc - mx);
        float inv = 1.f / sum;
        for (int j = 0; j < 64; ++j)
            lds_a[(h * 64 + row) * 64 + j] = (short)f2bf(__expf(gb[j] * sc - mx) * inv);
    }
    __syncthreads();

    for (int tt = 0; tt < 2; ++tt) {
        int ttile = tc * 2 + tt;
#pragma unroll
        for (int hh = 0; hh < 2; ++hh) {
            int h = wave * 2 + hh;
            const short* V = (const short*)v + (size_t)(b * 8 + h) * TT * HDIM;
            short8 bv[2];
#pragma unroll
            for (int kf = 0; kf < 2; ++kf)
                bv[kf] = *(const short8*)(V + (ttile * 16 + l15) * HDIM + kf * 32 + quad * 8);
#pragma unroll
            for (int g = 0; g < 4; ++g) {
                floatx4 c = (floatx4){0.f, 0.f, 0.f, 0.f};
#pragma unroll
                for (int kf = 0; kf < 2; ++kf) {
                    short8 pa = *(const short8*)&lds_a[(h * 64 + g * 16 + l15) * 64 + kf * 32 + quad * 8];
                    c = __builtin_amdgcn_mfma_f32_16x16x32_bf16(pa, bv[kf], c, 0, 0, 0);
                }
#pragma unroll
                for (int r = 0; r < 4; ++r) {
                    int crow = g * 16 + quad * 4 + r;
                    stg[crow * 128 + l15 * 8 + h] = (short)f2bf(c[r]);
                }
            }
        }
        __syncthreads();
        {
            int row = threadIdx.x >> 2, chunk = threadIdx.x & 3;
            int tout = row * 16 + (ttile >> 2);
            unsigned short* dst = vp + (size_t)(b * TP + 1 + tout) * (2 * DD) + 512 +
                                  (ttile & 3) * 128 + chunk * 32;
            const short* src = &stg[row * 128 + chunk * 32];
#pragma unroll
            for (int e = 0; e < 4; ++e)
                *(short8*)&dst[e * 8] = *(const short8*)&src[e * 8];
        }
        __syncthreads();
    }
}

// ---------------- output conv: qkv-clone 64x64 tile, BK=64, 16 iters ---------------
// 1D grid 1024 = 4/CU (2x the old 128x64's residency — TLP hides the 2-phase drain,
// per R2/R11's occupancy lesson). LDS 20 KB, same staging/swizzle as qkv. XCD
// swizzle: 128 blocks/XCD = exactly one batch (vp panel L2-resident).
__global__ __launch_bounds__(256) void k_out_conv(
    const unsigned short* __restrict__ vp, const unsigned short* __restrict__ w2k,
    const float* __restrict__ b2, float* __restrict__ out) {
    __shared__ short As[2][80 * 64];
    int wave = threadIdx.x >> 6, lane = threadIdx.x & 63;
    int l15 = lane & 15, quad = lane >> 4;
    int i = blockIdx.x;
    int w = (i & 7) * 128 + (i >> 3);   // one batch per XCD
    int tb = (w & 15) * 64;
    int cb = ((w >> 4) & 7) * 64;
    int b = w >> 7;
    const short* A = (const short*)vp + b * TP * DD2;
    const short* WF = (const short*)w2k + lane * 8;
    int srow8 = lane >> 3;
    int scl = ((lane & 7) ^ srow8) * 8;
    int co0b = (cb >> 4) + wave;

    floatx4 acc[4];
#pragma unroll
    for (int mi = 0; mi < 4; ++mi) acc[mi] = (floatx4){0.f, 0.f, 0.f, 0.f};

    auto stage = [&](int it) {
        short* dst = As[it & 1];
        int cib = it * 64;
        for (int g = wave; g < 10; g += 4) {
            int j = g >> 1, hf = g & 1;
            int row = hf * 8 + srow8;
            gl2lds16(A + (tb + j * 16 + row) * DD2 + cib + scl, &dst[j * 1024 + hf * 512]);
        }
    };

    stage(0);
    __syncthreads();

    for (int it = 0; it < 16; ++it) {
        if (it < 15) stage(it + 1);
        const short* Asb = As[it & 1];
#pragma unroll
        for (int k = 0; k < 3; ++k) {
            short8 bf[2];
#pragma unroll
            for (int kf = 0; kf < 2; ++kf)
                bf[kf] = *(const short8*)(WF +
                    ((size_t)((k * 32 + it * 2 + kf) * 32 + co0b) << 9));
#pragma unroll
            for (int kf = 0; kf < 2; ++kf) {
                short8 af[4];
#pragma unroll
                for (int mi = 0; mi < 4; ++mi) {
                    int arow = mi * 16 + l15 + k;
                    int cl = kf * 4 + quad;
                    af[mi] = *(const short8*)&Asb[arow * 64 + ((cl ^ (arow & 7)) << 3)];
                }
#pragma unroll
                for (int mi = 0; mi < 4; ++mi)
                    acc[mi] = __builtin_amdgcn_mfma_f32_16x16x32_bf16(af[mi], bf[kf], acc[mi], 0, 0, 0);
            }
        }
        __syncthreads();
    }

    {
        int co = cb + wave * 16 + l15;
        float bv = b2[co];
#pragma unroll
        for (int mi = 0; mi < 4; ++mi) {
#pragma unroll
            for (int r = 0; r < 4; ++r) {
                int t = tb + mi * 16 + quad * 4 + r;
                out[((size_t)b * TT + t) * DD + co] = fmaxf(acc[mi][r] + bv, 0.f);
            }
        }
    }
}

extern "C" void kernel_launch(void* const* d_in, const int* in_sizes, int n_in,
                              void* d_out, int out_size, void* d_ws, size_t ws_size,
                              hipStream_t stream) {
    const float* x = (const float*)d_in[0];
    const float* w11 = (const float*)d_in[1];
    const float* b11 = (const float*)d_in[2];
    const float* w12 = (const float*)d_in[3];
    const float* b12 = (const float*)d_in[4];
    const float* w13 = (const float*)d_in[5];
    const float* b13 = (const float*)d_in[6];
    const float* w2 = (const float*)d_in[7];
    const float* b2 = (const float*)d_in[8];
    float* out = (float*)d_out;

    char* ws = (char*)d_ws;
    size_t off = 0;
    auto alloc = [&](size_t bytes) {
        void* p = ws + off;
        off += (bytes + 255) & ~(size_t)255;
        return p;
    };
    unsigned short* xp = (unsigned short*)alloc((size_t)BB * TP * DD * 2);
    unsigned short* wqkv = (unsigned short*)alloc((size_t)9 * DD * DD * 2);
    unsigned short* w2k = (unsigned short*)alloc((size_t)3 * DD * DD2 * 2);
    unsigned short* q = (unsigned short*)alloc((size_t)BB * HH * TT * HDIM * 2);
    unsigned short* qt = (unsigned short*)alloc((size_t)BB * HH * TT * HDIM * 2);
    unsigned short* kfrag = (unsigned short*)alloc((size_t)BB * HH * TT * HDIM * 2);
    unsigned short* kt = (unsigned short*)alloc((size_t)BB * HH * TT * HDIM * 2);
    unsigned short* v = (unsigned short*)alloc((size_t)BB * HH * TT * HDIM * 2);
    unsigned short* vtfrag = (unsigned short*)alloc((size_t)BB * HH * TT * HDIM * 2);
    float* gbuf = (float*)alloc((size_t)64 * HDIM * HDIM * 4);
    unsigned short* vp = (unsigned short*)alloc((size_t)BB * TP * 2 * DD * 2);
    (void)alloc(65536);  // guard: halo staging reads up to 15 rows past buffer ends

    k_prep<<<NX4BLK + NW1BLK + NW2BLK + NZBLK, 256, 0, stream>>>(x, w11, w12, w13, w2,
                                                                 xp, wqkv, w2k, vp, gbuf);
    k_qkv_conv<<<1536, 256, 0, stream>>>(xp, wqkv, b11, b12, b13,
                                         q, qt, kfrag, kt, v, vtfrag);
    k_attn_gram<<<1088, 256, 0, stream>>>(q, kfrag, vtfrag, qt, kt, gbuf, vp);
    k_chan_av<<<dim3(32, BB), 256, 0, stream>>>(gbuf, v, vp);
    k_out_conv<<<1024, 256, 0, stream>>>(vp, w2k, b2, out);
}

// Round 18
// 210.965 us; speedup vs baseline: 1.0399x; 1.0399x over previous
//
#include <hip/hip_runtime.h>

#define BB 8
#define TT 1024
#define DD 512
#define DD2 1024
#define HH 8
#define HDIM 64
#define TP (TT + 2)

typedef short short8 __attribute__((ext_vector_type(8)));
typedef float floatx4 __attribute__((ext_vector_type(4)));

typedef const __attribute__((address_space(1))) unsigned int* gas_ptr;
typedef __attribute__((address_space(3))) unsigned int* las_ptr;

__device__ __forceinline__ unsigned short f2bf(float f) {
    union { float f; unsigned u; } v; v.f = f;
    unsigned r = v.u + 0x7fffu + ((v.u >> 16) & 1u);
    return (unsigned short)(r >> 16);
}

// async global->LDS, 16B per lane, LDS dst = wave-uniform base + lane*16
__device__ __forceinline__ void gl2lds16(const void* g, void* l) {
    __builtin_amdgcn_global_load_lds((gas_ptr)g, (las_ptr)l, 16, 0, 0);
}

// ---------------- fused prep kernel (R15-proven) ----------------
#define NX4BLK 2052   // 8*1026*512/8/256
#define NW1BLK 3072   // 9*512*512/3/256
#define NW2BLK 2048   // 3*512*1024/3/256
#define NZBLK 1024
__global__ void k_prep(const float* __restrict__ x, const float* __restrict__ w0,
                       const float* __restrict__ w1, const float* __restrict__ w2,
                       const float* __restrict__ wo,
                       unsigned short* __restrict__ xp, unsigned short* __restrict__ wqkv,
                       unsigned short* __restrict__ w2k, unsigned short* __restrict__ vp,
                       float* __restrict__ gbuf) {
    int blk = blockIdx.x;
    if (blk < NX4BLK) {
        int idx = blk * 256 + threadIdx.x;
        int c8 = idx & 63;          // DD/8 = 64 chunks per row
        int rt = idx >> 6;
        int row = rt % TP;
        int b = rt / TP;
        ushort4 o0 = {0, 0, 0, 0}, o1 = {0, 0, 0, 0};
        if (row >= 1 && row <= TT) {
            const float* src = &x[((size_t)(b * TT + row - 1)) * DD + c8 * 8];
            float4 va = *(const float4*)src;
            float4 vb = *(const float4*)(src + 4);
            o0.x = f2bf(va.x); o0.y = f2bf(va.y); o0.z = f2bf(va.z); o0.w = f2bf(va.w);
            o1.x = f2bf(vb.x); o1.y = f2bf(vb.y); o1.z = f2bf(vb.z); o1.w = f2bf(vb.w);
        }
        *(ushort4*)&xp[(size_t)idx * 8] = o0;
        *(ushort4*)&xp[(size_t)idx * 8 + 4] = o1;
        return;
    }
    blk -= NX4BLK;
    if (blk < NW1BLK) {
        // W(qkv) B-frag-major: [proj][k][ci0(16)][co0(32)][lane(64)][e(8)]
        int idx = blk * 256 + threadIdx.x;      // [0, 786432)
        int e = idx & 7;
        int lane = (idx >> 3) & 63;
        int co0 = (idx >> 9) & 31;
        int ci0 = (idx >> 14) & 15;
        int p = idx >> 18;
        int base18 = idx & 0x3FFFF;
        int co = co0 * 16 + (lane & 15);
        int ci = ci0 * 32 + (lane >> 4) * 8 + e;
        const float* w = (p == 0) ? w0 : ((p == 1) ? w1 : w2);
        size_t src = (size_t)(co * DD + ci) * 3;
        float t0 = w[src], t1 = w[src + 1], t2 = w[src + 2];
        wqkv[((size_t)(p * 3 + 0) << 18) + base18] = f2bf(t0);
        wqkv[((size_t)(p * 3 + 1) << 18) + base18] = f2bf(t1);
        wqkv[((size_t)(p * 3 + 2) << 18) + base18] = f2bf(t2);
        return;
    }
    blk -= NW1BLK;
    if (blk < NW2BLK) {
        // W2 B-frag-major: [k][ci0(32)][co0(32)][lane(64)][e(8)]; 3 taps per thread.
        int idx = blk * 256 + threadIdx.x;      // [0, 524288)
        int e = idx & 7;
        int lane = (idx >> 3) & 63;
        int co0 = (idx >> 9) & 31;
        int ci0 = (idx >> 14) & 31;
        int co = co0 * 16 + (lane & 15);
        int ci = ci0 * 32 + (lane >> 4) * 8 + e;
        size_t src = (size_t)(co * DD2 + ci) * 3;
        float t0 = wo[src], t1 = wo[src + 1], t2 = wo[src + 2];
        w2k[((size_t)0 << 19) + idx] = f2bf(t0);
        w2k[((size_t)1 << 19) + idx] = f2bf(t1);
        w2k[((size_t)2 << 19) + idx] = f2bf(t2);
        return;
    }
    blk -= NW2BLK;
    {
        int idx = blk * 256 + threadIdx.x;
        if (idx < BB * 2 * 2 * DD) {
            int c = idx % (2 * DD);
            int t1 = idx / (2 * DD);
            int row = (t1 & 1) ? (TT + 1) : 0;
            int b = t1 >> 1;
            vp[(b * TP + row) * (2 * DD) + c] = 0;
        }
        if (idx < 64 * HDIM * HDIM) gbuf[idx] = 0.f;
    }
}

// ---------------- QKV conv: R3-proven 64x128 tile, BK=64 2-phase dbuf ----------
// 1D grid 1536 = 6/CU, XCD-swizzled (T1, R13-verified: FETCH 47->26.7 MB).
__global__ __launch_bounds__(256) void k_qkv_conv(
    const unsigned short* __restrict__ xp, const unsigned short* __restrict__ wfrag,
    const float* __restrict__ b11, const float* __restrict__ b12, const float* __restrict__ b13,
    unsigned short* __restrict__ q, unsigned short* __restrict__ qt,
    unsigned short* __restrict__ kfrag, unsigned short* __restrict__ kt,
    unsigned short* __restrict__ v, unsigned short* __restrict__ vtfrag) {
    __shared__ short As[2][80 * 64];
    int wave = threadIdx.x >> 6, lane = threadIdx.x & 63;
    int l15 = lane & 15, quad = lane >> 4;
    int i = blockIdx.x;
    int w = (i & 7) * 192 + (i >> 3);   // XCD-contiguous work chunks
    int tb = (w & 15) * 64;
    int cb = ((w >> 4) & 3) * 128;
    int z = w >> 6;
    int proj = z % 3, b = z / 3;
    const short* A = (const short*)xp + b * TP * DD;
    const short* WF = (const short*)wfrag + (size_t)proj * 786432 + lane * 8;
    int srow8 = lane >> 3;
    int scl = ((lane & 7) ^ srow8) * 8;
    int co0b = (cb >> 4) + wave * 2;

    floatx4 acc[4][2];
#pragma unroll
    for (int mi = 0; mi < 4; ++mi)
#pragma unroll
        for (int ni = 0; ni < 2; ++ni) acc[mi][ni] = (floatx4){0.f, 0.f, 0.f, 0.f};

    auto stage = [&](int it) {
        short* dst = As[it & 1];
        int cib = it * 64;
        for (int g = wave; g < 10; g += 4) {
            int j = g >> 1, hf = g & 1;
            int row = hf * 8 + srow8;
            gl2lds16(A + (tb + j * 16 + row) * DD + cib + scl, &dst[j * 1024 + hf * 512]);
        }
    };

    stage(0);
    __syncthreads();

    for (int it = 0; it < 8; ++it) {
        if (it < 7) stage(it + 1);
        const short* Asb = As[it & 1];
#pragma unroll
        for (int k = 0; k < 3; ++k) {
            short8 bf[2][2];
#pragma unroll
            for (int kf = 0; kf < 2; ++kf)
#pragma unroll
                for (int ni = 0; ni < 2; ++ni)
                    bf[kf][ni] = *(const short8*)(WF +
                        ((size_t)((k * 16 + it * 2 + kf) * 32 + co0b + ni) << 9));
#pragma unroll
            for (int kf = 0; kf < 2; ++kf) {
                short8 af[4];
#pragma unroll
                for (int mi = 0; mi < 4; ++mi) {
                    int arow = mi * 16 + l15 + k;
                    int cl = kf * 4 + quad;
                    af[mi] = *(const short8*)&Asb[arow * 64 + ((cl ^ (arow & 7)) << 3)];
                }
#pragma unroll
                for (int mi = 0; mi < 4; ++mi)
#pragma unroll
                    for (int ni = 0; ni < 2; ++ni)
                        acc[mi][ni] = __builtin_amdgcn_mfma_f32_16x16x32_bf16(af[mi], bf[kf][ni], acc[mi][ni], 0, 0, 0);
            }
        }
        __syncthreads();
    }

    const float* bias = (proj == 0) ? b11 : ((proj == 1) ? b12 : b13);
#pragma unroll
    for (int ni = 0; ni < 2; ++ni) {
        int co = cb + wave * 32 + ni * 16 + l15;
        float bv = bias[co];
        int h = co >> 6, hd = co & 63;
        int bh = b * HH + h;
#pragma unroll
        for (int mi = 0; mi < 4; ++mi) {
            int tbase = tb + mi * 16 + quad * 4;
            unsigned short bb[4];
            ushort4 pk;
#pragma unroll
            for (int r = 0; r < 4; ++r) {
                float val = fmaxf(acc[mi][ni][r] + bv, 0.f);
                bb[r] = f2bf(val);
                ((unsigned short*)&pk)[r] = bb[r];
            }
            if (proj == 0) {
#pragma unroll
                for (int r = 0; r < 4; ++r)
                    q[((size_t)bh * TT + tbase + r) * HDIM + hd] = bb[r];
                *(ushort4*)&qt[((size_t)bh * HDIM + hd) * TT + tbase] = pk;
            } else if (proj == 1) {
                *(ushort4*)&kt[((size_t)bh * HDIM + hd) * TT + tbase] = pk;
                // K-frag layout: [bh][sblk][jr][kf][quad_a*16+l15a][8]
                int sblk = tbase >> 6;
                int jr = (quad & 1) + 2 * (mi >> 1);
                int l15a_base = 4 * (quad >> 1) + 8 * (mi & 1);  // + r
                int kf = hd >> 5, quad_a = (hd >> 3) & 3, elem = hd & 7;
                size_t base = ((((size_t)bh * 16 + sblk) * 4 + jr) * 2 + kf) * 512 +
                              quad_a * 128 + elem;
#pragma unroll
                for (int r = 0; r < 4; ++r)
                    kfrag[base + (l15a_base + r) * 8] = bb[r];
            } else {
#pragma unroll
                for (int r = 0; r < 4; ++r)
                    v[((size_t)bh * TT + tbase + r) * HDIM + hd] = bb[r];
                // Vt-frag layout: [bh][sblk][df][kf][quad_a*16+l15a][8]
                int sblk = tbase >> 6;
                int df = hd >> 4, l15a = hd & 15;
                int kf = mi >> 1;
                int quad_a = 2 * (mi & 1) + (quad >> 1);
                int elem = (quad & 1) * 4;
                size_t base = ((((size_t)bh * 16 + sblk) * 4 + df) * 2 + kf) * 512 +
                              (quad_a * 16 + l15a) * 8 + elem;
                *(ushort4*)&vtfrag[base] = pk;
            }
        }
    }
}

// ---------------- fused: time attention (x<16) + chan Gram partials (x>=16) ----------
// 1D grid 1280, XCD-swizzled (T1): each XCD gets 8 consecutive bh's. (R14-proven)
__global__ __launch_bounds__(256) void k_attn_gram(
    const unsigned short* __restrict__ q, const unsigned short* __restrict__ kfrag,
    const unsigned short* __restrict__ vtfrag, const unsigned short* __restrict__ qt,
    const unsigned short* __restrict__ kt, float* __restrict__ gbuf,
    unsigned short* __restrict__ vp) {
    __shared__ short kvs[2][8192];  // [buf][ K frags 0..4095 | V frags 4096..8191 ]
    int wave = threadIdx.x >> 6, lane = threadIdx.x & 63;
    int l15 = lane & 15, quad = lane >> 4;
    int i = blockIdx.x;
    int w = (i & 7) * 160 + (i >> 3);   // XCD-contiguous chunks of 8 bh
    int bh = w / 20;
    int x = w % 20;

    if (x < 16) {
        // ---- time attention: all-register flash, LDS-staged K/V frags ----
        int b = bh >> 3, h = bh & 7;
        int qr = x * 64 + wave * 16;
        const short* Q = (const short*)q + (size_t)bh * TT * HDIM;
        const short* KF = (const short*)kfrag + (size_t)bh * 16 * 8 * 512 + lane * 8;
        const short* VF = (const short*)vtfrag + (size_t)bh * 16 * 8 * 512 + lane * 8;

        short8 bq[2];
#pragma unroll
        for (int kf = 0; kf < 2; ++kf)
            bq[kf] = *(const short8*)(Q + (qr + l15) * HDIM + kf * 32 + quad * 8);

        floatx4 o[4];  // O^T accum: d = df*16 + quad*4 + r, q = l15
#pragma unroll
        for (int df = 0; df < 4; ++df) o[df] = (floatx4){0.f, 0.f, 0.f, 0.f};
        float lacc = 0.f;

        auto stagekv = [&](int s) {
            short* dst = kvs[s & 1];
            for (int f = wave; f < 8; f += 4) {
                gl2lds16(KF + s * 4096 + f * 512, &dst[f * 512]);
                gl2lds16(VF + s * 4096 + f * 512, &dst[4096 + f * 512]);
            }
        };

        stagekv(0);
        __syncthreads();

        for (int sblk = 0; sblk < 16; ++sblk) {
            if (sblk < 15) stagekv(sblk + 1);
            const short* kb = (const short*)&kvs[sblk & 1][0] + lane * 8;
            const short* vb = kb + 4096;
            floatx4 c[4];
#pragma unroll
            for (int jr = 0; jr < 4; ++jr) c[jr] = (floatx4){0.f, 0.f, 0.f, 0.f};
#pragma unroll
            for (int jr = 0; jr < 4; ++jr) {
#pragma unroll
                for (int kf = 0; kf < 2; ++kf) {
                    short8 ak = *(const short8*)(kb + (jr * 2 + kf) * 512);
                    c[jr] = __builtin_amdgcn_mfma_f32_16x16x32_bf16(ak, bq[kf], c[jr], 0, 0, 0);
                }
            }
            short8 pb[2];
#pragma unroll
            for (int kf = 0; kf < 2; ++kf) {
                union { short8 s; unsigned u[4]; } pk;
#pragma unroll
                for (int half = 0; half < 2; ++half) {
                    floatx4 cc = c[2 * kf + half];
                    float p0 = __expf(cc[0] * 0.125f);
                    float p1 = __expf(cc[1] * 0.125f);
                    float p2 = __expf(cc[2] * 0.125f);
                    float p3 = __expf(cc[3] * 0.125f);
                    lacc += (p0 + p1) + (p2 + p3);
                    pk.u[half * 2] =
                        __builtin_amdgcn_perm(__float_as_uint(p1), __float_as_uint(p0), 0x07060302u);
                    pk.u[half * 2 + 1] =
                        __builtin_amdgcn_perm(__float_as_uint(p3), __float_as_uint(p2), 0x07060302u);
                }
                pb[kf] = pk.s;
            }
#pragma unroll
            for (int df = 0; df < 4; ++df) {
#pragma unroll
                for (int kf = 0; kf < 2; ++kf) {
                    short8 av = *(const short8*)(vb + (df * 2 + kf) * 512);
                    o[df] = __builtin_amdgcn_mfma_f32_16x16x32_bf16(av, pb[kf], o[df], 0, 0, 0);
                }
            }
            __syncthreads();
        }

        lacc += __shfl_xor(lacc, 16);
        lacc += __shfl_xor(lacc, 32);
        float linv = 1.f / lacc;

        unsigned short* vrow = vp + (size_t)(b * TP + 1 + qr + l15) * (2 * DD) + h * 64;
#pragma unroll
        for (int df = 0; df < 4; ++df) {
            ushort4 pk;
#pragma unroll
            for (int r = 0; r < 4; ++r) ((unsigned short*)&pk)[r] = f2bf(o[df][r] * linv);
            *(ushort4*)&vrow[df * 16 + quad * 4] = pk;
        }
    } else {
        // ---- chan Gram partials (4-way T split) ----
        int tc = x - 16;
        const short* Qt = (const short*)qt + (size_t)bh * HDIM * TT;
        const short* Kt = (const short*)kt + (size_t)bh * HDIM * TT;

        floatx4 g[4];
#pragma unroll
        for (int nt = 0; nt < 4; ++nt) g[nt] = (floatx4){0.f, 0.f, 0.f, 0.f};

        int t0b = tc * 256;
        for (int t0 = 0; t0 < 256; t0 += 32) {
            short8 aq = *(const short8*)(Qt + (wave * 16 + l15) * TT + t0b + t0 + quad * 8);
#pragma unroll
            for (int nt = 0; nt < 4; ++nt) {
                short8 bk = *(const short8*)(Kt + (nt * 16 + l15) * TT + t0b + t0 + quad * 8);
                g[nt] = __builtin_amdgcn_mfma_f32_16x16x32_bf16(aq, bk, g[nt], 0, 0, 0);
            }
        }
        float* gb = gbuf + bh * HDIM * HDIM;
#pragma unroll
        for (int nt = 0; nt < 4; ++nt) {
#pragma unroll
            for (int r = 0; r < 4; ++r) {
                int row = wave * 16 + quad * 4 + r;
                atomicAdd(&gb[row * HDIM + nt * 16 + l15], g[nt][r]);
            }
        }
    }
}

// ---------------- channel attention: all-8-heads blocks, coalesced vp writes --------
// grid (32, B=8) = 256 blocks = 1/CU. Full-line vp writes from one block. (R7/R10-proven)
__global__ __launch_bounds__(256) void k_chan_av(
    const float* __restrict__ gbuf, const unsigned short* __restrict__ v,
    unsigned short* __restrict__ vp) {
    __shared__ short lds_a[8 * 64 * 64];   // 64 KB
    __shared__ short stg[64 * 128];        // 16 KB
    int wave = threadIdx.x >> 6, lane = threadIdx.x & 63;
    int l15 = lane & 15, quad = lane >> 4;
    int tc = blockIdx.x, b = blockIdx.y;
    const float sc = 0.03125f;  // 1/sqrt(1024)

    // softmax for all 8 heads: 512 rows over 256 threads
    for (int p = threadIdx.x; p < 512; p += 256) {
        int h = p >> 6, row = p & 63;
        const float* gb = gbuf + (size_t)((b * 8 + h) * 64 + row) * 64;
        float mx = -3.0e38f;
        for (int j = 0; j < 16; ++j) {
            float4 vv = *(const float4*)&gb[j * 4];
            mx = fmaxf(mx, fmaxf(fmaxf(vv.x, vv.y), fmaxf(vv.z, vv.w)));
        }
        mx *= sc;
        float sum = 0.f;
        for (int j = 0; j < 64; ++j) sum += __expf(gb[j] * sc - mx);
        float inv = 1.f / sum;
        for (int j = 0; j < 64; ++j)
            lds_a[(h * 64 + row) * 64 + j] = (short)f2bf(__expf(gb[j] * sc - mx) * inv);
    }
    __syncthreads();

    for (int tt = 0; tt < 2; ++tt) {
        int ttile = tc * 2 + tt;
#pragma unroll
        for (int hh = 0; hh < 2; ++hh) {
            int h = wave * 2 + hh;
            const short* V = (const short*)v + (size_t)(b * 8 + h) * TT * HDIM;
            short8 bv[2];
#pragma unroll
            for (int kf = 0; kf < 2; ++kf)
                bv[kf] = *(const short8*)(V + (ttile * 16 + l15) * HDIM + kf * 32 + quad * 8);
#pragma unroll
            for (int g = 0; g < 4; ++g) {
                floatx4 c = (floatx4){0.f, 0.f, 0.f, 0.f};
#pragma unroll
                for (int kf = 0; kf < 2; ++kf) {
                    short8 pa = *(const short8*)&lds_a[(h * 64 + g * 16 + l15) * 64 + kf * 32 + quad * 8];
                    c = __builtin_amdgcn_mfma_f32_16x16x32_bf16(pa, bv[kf], c, 0, 0, 0);
                }
#pragma unroll
                for (int r = 0; r < 4; ++r) {
                    int crow = g * 16 + quad * 4 + r;
                    stg[crow * 128 + l15 * 8 + h] = (short)f2bf(c[r]);
                }
            }
        }
        __syncthreads();
        {
            int row = threadIdx.x >> 2, chunk = threadIdx.x & 3;
            int tout = row * 16 + (ttile >> 2);
            unsigned short* dst = vp + (size_t)(b * TP + 1 + tout) * (2 * DD) + 512 +
                                  (ttile & 3) * 128 + chunk * 32;
            const short* src = &stg[row * 128 + chunk * 32];
#pragma unroll
            for (int e = 0; e < 4; ++e)
                *(short8*)&dst[e * 8] = *(const short8*)&src[e * 8];
        }
        __syncthreads();
    }
}

// ---------------- output conv: R14-proven 128x64 tile, BK=64, 2-phase dbuf ---------
// 1D grid 512, XCD-swizzled (T1): one batch per XCD. (Tile-geometry search closed:
// BK=128 +17.5 us (R11), 64x64 +5.3 us (R16) — this shape is the balanced point.)
__global__ __launch_bounds__(256) void k_out_conv(
    const unsigned short* __restrict__ vp, const unsigned short* __restrict__ w2k,
    const float* __restrict__ b2, float* __restrict__ out) {
    __shared__ short As[2][144 * 64];
    int wave = threadIdx.x >> 6, lane = threadIdx.x & 63;
    int l15 = lane & 15, quad = lane >> 4;
    int wm = wave >> 1, wn = wave & 1;
    int i = blockIdx.x;
    int w = (i & 7) * 64 + (i >> 3);    // XCD-contiguous chunks of one batch
    int tb = (w & 7) * 128;
    int cb = ((w >> 3) & 7) * 64;
    int b = w >> 6;
    const short* A = (const short*)vp + b * TP * DD2;
    const short* WF = (const short*)w2k + lane * 8;
    int srow8 = lane >> 3;
    int scl = ((lane & 7) ^ srow8) * 8;
    int co0b = (cb >> 4) + wn * 2;

    floatx4 acc[4][2];
#pragma unroll
    for (int mi = 0; mi < 4; ++mi)
#pragma unroll
        for (int ni = 0; ni < 2; ++ni) acc[mi][ni] = (floatx4){0.f, 0.f, 0.f, 0.f};

    auto stage = [&](int it) {
        short* dst = As[it & 1];
        int cib = it * 64;
        for (int g = wave; g < 18; g += 4) {
            int j = g >> 1, hf = g & 1;
            int row = hf * 8 + srow8;
            gl2lds16(A + (tb + j * 16 + row) * DD2 + cib + scl, &dst[j * 1024 + hf * 512]);
        }
    };

    stage(0);
    __syncthreads();

    for (int it = 0; it < 16; ++it) {
        if (it < 15) stage(it + 1);
        const short* Asb = As[it & 1];
#pragma unroll
        for (int k = 0; k < 3; ++k) {
            short8 bf[2][2];
#pragma unroll
            for (int kfh = 0; kfh < 2; ++kfh)
#pragma unroll
                for (int ni = 0; ni < 2; ++ni)
                    bf[kfh][ni] = *(const short8*)(WF +
                        ((size_t)((k * 32 + it * 2 + kfh) * 32 + co0b + ni) << 9));
#pragma unroll
            for (int kfh = 0; kfh < 2; ++kfh) {
                short8 af[4];
#pragma unroll
                for (int mi = 0; mi < 4; ++mi) {
                    int arow = wm * 64 + mi * 16 + l15 + k;
                    int cl = kfh * 4 + quad;
                    af[mi] = *(const short8*)&Asb[arow * 64 + ((cl ^ (arow & 7)) << 3)];
                }
#pragma unroll
                for (int mi = 0; mi < 4; ++mi)
#pragma unroll
                    for (int ni = 0; ni < 2; ++ni)
                        acc[mi][ni] = __builtin_amdgcn_mfma_f32_16x16x32_bf16(af[mi], bf[kfh][ni], acc[mi][ni], 0, 0, 0);
            }
        }
        __syncthreads();
    }

#pragma unroll
    for (int ni = 0; ni < 2; ++ni) {
        int co = cb + wn * 32 + ni * 16 + l15;
        float bv = b2[co];
#pragma unroll
        for (int mi = 0; mi < 4; ++mi) {
#pragma unroll
            for (int r = 0; r < 4; ++r) {
                int t = tb + wm * 64 + mi * 16 + quad * 4 + r;
                out[((size_t)b * TT + t) * DD + co] = fmaxf(acc[mi][ni][r] + bv, 0.f);
            }
        }
    }
}

extern "C" void kernel_launch(void* const* d_in, const int* in_sizes, int n_in,
                              void* d_out, int out_size, void* d_ws, size_t ws_size,
                              hipStream_t stream) {
    const float* x = (const float*)d_in[0];
    const float* w11 = (const float*)d_in[1];
    const float* b11 = (const float*)d_in[2];
    const float* w12 = (const float*)d_in[3];
    const float* b12 = (const float*)d_in[4];
    const float* w13 = (const float*)d_in[5];
    const float* b13 = (const float*)d_in[6];
    const float* w2 = (const float*)d_in[7];
    const float* b2 = (const float*)d_in[8];
    float* out = (float*)d_out;

    char* ws = (char*)d_ws;
    size_t off = 0;
    auto alloc = [&](size_t bytes) {
        void* p = ws + off;
        off += (bytes + 255) & ~(size_t)255;
        return p;
    };
    unsigned short* xp = (unsigned short*)alloc((size_t)BB * TP * DD * 2);
    unsigned short* wqkv = (unsigned short*)alloc((size_t)9 * DD * DD * 2);
    unsigned short* w2k = (unsigned short*)alloc((size_t)3 * DD * DD2 * 2);
    unsigned short* q = (unsigned short*)alloc((size_t)BB * HH * TT * HDIM * 2);
    unsigned short* qt = (unsigned short*)alloc((size_t)BB * HH * TT * HDIM * 2);
    unsigned short* kfrag = (unsigned short*)alloc((size_t)BB * HH * TT * HDIM * 2);
    unsigned short* kt = (unsigned short*)alloc((size_t)BB * HH * TT * HDIM * 2);
    unsigned short* v = (unsigned short*)alloc((size_t)BB * HH * TT * HDIM * 2);
    unsigned short* vtfrag = (unsigned short*)alloc((size_t)BB * HH * TT * HDIM * 2);
    float* gbuf = (float*)alloc((size_t)64 * HDIM * HDIM * 4);
    unsigned short* vp = (unsigned short*)alloc((size_t)BB * TP * 2 * DD * 2);
    (void)alloc(65536);  // guard: halo staging reads up to 15 rows past buffer ends

    k_prep<<<NX4BLK + NW1BLK + NW2BLK + NZBLK, 256, 0, stream>>>(x, w11, w12, w13, w2,
                                                                 xp, wqkv, w2k, vp, gbuf);
    k_qkv_conv<<<1536, 256, 0, stream>>>(xp, wqkv, b11, b12, b13,
                                         q, qt, kfrag, kt, v, vtfrag);
    k_attn_gram<<<1280, 256, 0, stream>>>(q, kfrag, vtfrag, qt, kt, gbuf, vp);
    k_chan_av<<<dim3(32, BB), 256, 0, stream>>>(gbuf, v, vp);
    k_out_conv<<<512, 256, 0, stream>>>(vp, w2k, b2, out);
}